// Round 8
// baseline (266.884 us; speedup 1.0000x reference)
//
#include <hip/hip_runtime.h>
#include <hip/hip_bf16.h>

typedef _Float16 f16;
typedef __attribute__((ext_vector_type(4))) _Float16 f16x4;
typedef __attribute__((ext_vector_type(8))) _Float16 f16x8;
typedef __attribute__((ext_vector_type(4))) float f32x4;

#define MFMA16(a, b, c) __builtin_amdgcn_mfma_f32_16x16x16f16((a), (b), (c), 0, 0, 0)
#define MFMA32(a, b, c) __builtin_amdgcn_mfma_f32_16x16x32_f16((a), (b), (c), 0, 0, 0)
#define EXP2(x) __builtin_amdgcn_exp2f(x)
#define GLOAD_LDS16(g, l)                                                        \
  __builtin_amdgcn_global_load_lds((const __attribute__((address_space(1))) void*)(g), \
                                   (__attribute__((address_space(3))) void*)(l), 16, 0, 0)
typedef const __attribute__((address_space(3))) char* lds_cp;
#define TR16(dst, addr, imm) \
  asm volatile("ds_read_b64_tr_b16 %0, %1 offset:" imm : "=v"(dst) : "v"(addr))

// ---------------- cast fp32 -> fp16 (vectorized) ----------------
__global__ __launch_bounds__(256) void cast_f32_f16_kernel(
    const float* __restrict__ in, f16* __restrict__ out, int n4) {
  int i = blockIdx.x * 256 + threadIdx.x;
  if (i >= n4) return;
  const float4 v = reinterpret_cast<const float4*>(in)[i];
  f16x4 h;
  h[0] = (f16)v.x; h[1] = (f16)v.y; h[2] = (f16)v.z; h[3] = (f16)v.w;
  reinterpret_cast<f16x4*>(out)[i] = h;
}

// ------------- transpose + cast: src[R][Cc] f32 -> dst[Cc][R] f16 -------------
__global__ __launch_bounds__(256) void transpose_cast_kernel(
    const float* __restrict__ src, f16* __restrict__ dst, int R, int Cc) {
  __shared__ float t[32][33];
  int tx0 = blockIdx.x * 32, ty0 = blockIdx.y * 32;
  int c = threadIdx.x & 31;
  int r0 = threadIdx.x >> 5;
#pragma unroll
  for (int i = 0; i < 4; i++) {
    int r = r0 + 8 * i;
    t[r][c] = src[(size_t)(ty0 + r) * Cc + tx0 + c];
  }
  __syncthreads();
#pragma unroll
  for (int i = 0; i < 4; i++) {
    int a = r0 + 8 * i;
    dst[(size_t)(tx0 + a) * R + ty0 + c] = (f16)t[c][a];
  }
}

// ============ 256x128 GEMM, 3 blocks/CU, perfect grid packing ============
// C[M][N] = A[M][K] * Bt[N][K]^T (f16). BK=32, 256 thr = 4 waves (2m x 2n),
// wave tile 128x64 (8mi x 4ni MFMA32 per K-tile). LDS 48KB = 2buf x [A16K|B8K].
// Layout: row-pair packed — logical (row, k16) lives at byte
//   (row>>1)*128 + ((((row&1)*4 + k16) ^ ((row>>1)&7)) * 16)
// => b128 fragment reads spread 64 lanes uniformly 8/slot-group (conflict-free);
// staged via global_load_lds with inverse-permuted source, linear dest.
__global__ __launch_bounds__(256, 3) void gemm_bt_kernel(
    const f16* __restrict__ A, const f16* __restrict__ Bt, f16* __restrict__ C,
    int M, int N, int K) {
  __shared__ __align__(16) char smem[49152];
  const int tid = threadIdx.x;
  const int lane = tid & 63, wid = tid >> 6;
  const int wm = wid >> 1, wn = wid & 1;
  const int lo = lane & 15, hi = lane >> 4;

  // XCD-bijective block swizzle (grid % 8 == 0)
  const int ntn = N >> 7;
  const int nwg = (M >> 8) * ntn;
  const int wg = (blockIdx.x & 7) * (nwg >> 3) + (blockIdx.x >> 3);
  const int tm0 = (wg / ntn) << 8, tn0 = (wg % ntn) << 7;

  // staging source pointers (6 loads/thread/K-tile: A x4, B x2)
  const f16* asrc[4];
  const f16* bsrc[2];
#pragma unroll
  for (int i = 0; i < 4; i++) {
    int L = tid + 256 * i;            // A linear 16B slot 0..1023
    int prow = L >> 3, u = (L & 7) ^ (prow & 7);
    int grow = prow * 2 + (u >> 2), gk8 = u & 3;
    asrc[i] = A + (size_t)(tm0 + grow) * K + gk8 * 8;
  }
#pragma unroll
  for (int i = 0; i < 2; i++) {
    int L = tid + 256 * i;            // B linear 16B slot 0..511
    int prow = L >> 3, u = (L & 7) ^ (prow & 7);
    int grow = prow * 2 + (u >> 2), gk8 = u & 3;
    bsrc[i] = Bt + (size_t)(tn0 + grow) * K + gk8 * 8;
  }

  // fragment LDS byte offsets (lane-constant; mi/ni add 1024B immediates)
  const int slot = ((lo & 1) * 4 + hi) ^ ((lo >> 1) & 7);
  const int abyte = (wm * 64 + (lo >> 1)) * 128 + slot * 16;
  const int bbyte = 16384 + (wn * 32 + (lo >> 1)) * 128 + slot * 16;

  f32x4 acc[8][4] = {};

  auto stage = [&](int kt, char* buf) {
#pragma unroll
    for (int i = 0; i < 4; i++)
      GLOAD_LDS16(asrc[i] + kt, buf + (tid + 256 * i) * 16);
#pragma unroll
    for (int i = 0; i < 2; i++)
      GLOAD_LDS16(bsrc[i] + kt, buf + 16384 + (tid + 256 * i) * 16);
  };

  const int NT = K >> 5;
  stage(0, smem);

  for (int t = 0; t < NT; t++) {
    char* db = smem + (t & 1) * 24576;
    asm volatile("s_waitcnt vmcnt(0)" ::: "memory");  // tile t landed (issued 1 iter ago)
    __builtin_amdgcn_s_barrier();
    if (t + 1 < NT) stage((t + 1) * 32, smem + ((t + 1) & 1) * 24576);
    __builtin_amdgcn_sched_barrier(0);  // keep prefetch issue ahead of reads/MFMA

    f16x8 a[8], b[4];
#pragma unroll
    for (int mi = 0; mi < 8; mi++) a[mi] = *(const f16x8*)(db + abyte + mi * 1024);
#pragma unroll
    for (int ni = 0; ni < 4; ni++) b[ni] = *(const f16x8*)(db + bbyte + ni * 1024);
    __builtin_amdgcn_s_setprio(1);
#pragma unroll
    for (int mi = 0; mi < 8; mi++)
#pragma unroll
      for (int ni = 0; ni < 4; ni++)
        acc[mi][ni] = MFMA32(a[mi], b[ni], acc[mi][ni]);
    __builtin_amdgcn_s_setprio(0);
  }

  // epilogue
#pragma unroll
  for (int mi = 0; mi < 8; mi++)
#pragma unroll
    for (int ni = 0; ni < 4; ni++)
#pragma unroll
      for (int r = 0; r < 4; r++) {
        int row = tm0 + wm * 128 + mi * 16 + 4 * hi + r;
        int col = tn0 + wn * 64 + ni * 16 + lo;
        C[(size_t)row * N + col] = (f16)acc[mi][ni][r];
      }
}

// ---------------- GEMM (128^2, triple-buffered counted vmcnt) — proj ----------------
template <bool OUT_F32>
__global__ __launch_bounds__(256) void gemm_f16_kernel(
    const f16* __restrict__ A, const f16* __restrict__ Bt, void* __restrict__ Cout,
    int M, int N, int K) {
  constexpr int BK = 32;
  __shared__ f16 Al[3][128 * BK];
  __shared__ f16 Bl[3][128 * BK];

  const int tid = threadIdx.x;
  const int lane = tid & 63, wid = tid >> 6;
  const int wm = wid >> 1, wn = wid & 1;
  const int lo = lane & 15, hi = lane >> 4;
  const int tn0 = blockIdx.x * 128, tm0 = blockIdx.y * 128;

  f32x4 acc[4][4] = {};

  const int r1 = tid >> 2, o1 = (tid & 3) * 8;

  auto stage = [&](int kt, int c) {
    GLOAD_LDS16(&A[(size_t)(tm0 + r1) * K + kt + o1], &Al[c][tid * 8]);
    GLOAD_LDS16(&A[(size_t)(tm0 + r1 + 64) * K + kt + o1], &Al[c][(tid + 256) * 8]);
    GLOAD_LDS16(&Bt[(size_t)(tn0 + r1) * K + kt + o1], &Bl[c][tid * 8]);
    GLOAD_LDS16(&Bt[(size_t)(tn0 + r1 + 64) * K + kt + o1], &Bl[c][(tid + 256) * 8]);
  };

  auto compute = [&](int cur) {
    f16x8 af[4], bf[4];
#pragma unroll
    for (int mi = 0; mi < 4; mi++)
      af[mi] = *(const f16x8*)&Al[cur][(wm * 64 + mi * 16 + lo) * BK + 8 * hi];
#pragma unroll
    for (int ni = 0; ni < 4; ni++)
      bf[ni] = *(const f16x8*)&Bl[cur][(wn * 64 + ni * 16 + lo) * BK + 8 * hi];
    __builtin_amdgcn_s_setprio(1);
#pragma unroll
    for (int mi = 0; mi < 4; mi++)
#pragma unroll
      for (int ni = 0; ni < 4; ni++)
        acc[mi][ni] = MFMA32(af[mi], bf[ni], acc[mi][ni]);
    __builtin_amdgcn_s_setprio(0);
  };

  const int NT = K / BK;
  stage(0, 0);
  stage(BK, 1);

  int cur = 0;
  for (int t = 0; t < NT - 1; t++) {
    asm volatile("s_waitcnt vmcnt(4)" ::: "memory");
    __builtin_amdgcn_s_barrier();
    if (t + 2 < NT) stage((t + 2) * BK, (t + 2) % 3);
    compute(cur);
    cur = (cur == 2) ? 0 : cur + 1;
  }
  asm volatile("s_waitcnt vmcnt(0)" ::: "memory");
  __builtin_amdgcn_s_barrier();
  compute(cur);

#pragma unroll
  for (int mi = 0; mi < 4; mi++)
#pragma unroll
    for (int ni = 0; ni < 4; ni++)
#pragma unroll
      for (int r = 0; r < 4; r++) {
        int row = tm0 + wm * 64 + mi * 16 + 4 * hi + r;
        int col = tn0 + wn * 64 + ni * 16 + lo;
        float v = acc[mi][ni][r];
        if (OUT_F32)
          ((float*)Cout)[(size_t)row * N + col] = v;
        else
          ((f16*)Cout)[(size_t)row * N + col] = (f16)v;
      }
}

// ---------------- causal flash attention ----------------
__global__ __launch_bounds__(256, 4) void attn_kernel(
    const f16* __restrict__ qkv, f16* __restrict__ y) {
  constexpr int T = 2048, NHD = 3072, LDO = 72;
  const int bh = blockIdx.x;
  const int b = bh >> 4, h = bh & 15;
  const int pr = blockIdx.y;
  const int tid = threadIdx.x;
  const int lane = tid & 63, w = tid >> 6;
  const int lo = lane & 15, hi = lane >> 4;

  const size_t base = (size_t)b * T * NHD + (size_t)h * 64;
  const f16* Qp = qkv + base;
  const f16* Kp = qkv + base + 1024;
  const f16* Vp = qkv + base + 2048;

  __shared__ __align__(16) char smem[32768];
  f16 (*Ol)[LDO] = (f16(*)[LDO])smem;

  const int tile[2] = {pr, 31 - pr};
  const int qb[2] = {tile[0] * 64 + w * 16, tile[1] * 64 + w * 16};

  const float scf = 0.125f * 1.44269504089f;
  f16x8 qf[2][2];
#pragma unroll
  for (int s = 0; s < 2; s++) {
    const f16* qrow = Qp + (size_t)(qb[s] + lo) * NHD;
#pragma unroll
    for (int ks = 0; ks < 2; ks++) {
      f16x8 v = *(const f16x8*)&qrow[ks * 32 + 8 * hi];
#pragma unroll
      for (int j = 0; j < 8; j++) v[j] = (f16)((float)v[j] * scf);
      qf[s][ks] = v;
    }
  }

  f32x4 oacc[2][4] = {};
  float mreg[2] = {-1e30f, -1e30f};
  float lsum[2] = {0.f, 0.f};

  const int kr = tid >> 3;
  const int kslot = (tid & 7) ^ (kr & 7);
  const int tp = tid & 127;
  const int vkey = 4 * (tp >> 3) + ((tp >> 1) & 3);
  const int vcol = (tid >> 7) * 16 + (tid & 1) * 8;

  const int kfo0 = lo * 64 + ((hi ^ (lo & 7)) * 8);
  const int kfo1 = lo * 64 + (((4 + hi) ^ (lo & 7)) * 8);

  auto stage = [&](int kv, int c) {
    char* kb = smem + c * 8192;
    char* vb = smem + 16384 + c * 8192;
    GLOAD_LDS16(&Kp[(size_t)(kv + kr) * NHD + kslot * 8], kb + tid * 16);
    GLOAD_LDS16(&Kp[(size_t)(kv + kr + 32) * NHD + kslot * 8], kb + 4096 + tid * 16);
    GLOAD_LDS16(&Vp[(size_t)(kv + vkey) * NHD + vcol], vb + tid * 16);
    GLOAD_LDS16(&Vp[(size_t)(kv + vkey) * NHD + vcol + 32], vb + 4096 + tid * 16);
  };

  const int nt = 32 - pr;
  stage(0, 0);
  asm volatile("s_waitcnt vmcnt(0)" ::: "memory");
  __builtin_amdgcn_s_barrier();

  for (int t = 0; t < nt; t++) {
    const int cur = t & 1;
    const int kv0 = t * 64;
    if (t + 1 < nt) stage(kv0 + 64, cur ^ 1);

    const f16* Kl = (const f16*)(smem + cur * 8192);
    const bool act0 = kv0 <= qb[0] + 15;

    f16x8 kf[2][4];
#pragma unroll
    for (int ct = 0; ct < 4; ct++) {
      kf[0][ct] = *(const f16x8*)&Kl[ct * 1024 + kfo0];
      kf[1][ct] = *(const f16x8*)&Kl[ct * 1024 + kfo1];
    }

    f16x4 pb[2][4];
#pragma unroll
    for (int s = 0; s < 2; s++) {
      if (s == 0 && !act0) continue;
      f32x4 s_[4] = {};
      __builtin_amdgcn_s_setprio(1);
#pragma unroll
      for (int ks = 0; ks < 2; ks++)
#pragma unroll
        for (int ct = 0; ct < 4; ct++)
          s_[ct] = MFMA32(kf[ks][ct], qf[s][ks], s_[ct]);
      __builtin_amdgcn_s_setprio(0);

      if (kv0 + 63 > qb[s]) {
        const int q = qb[s] + lo;
#pragma unroll
        for (int ct = 0; ct < 4; ct++)
#pragma unroll
          for (int r = 0; r < 4; r++)
            if (kv0 + ct * 16 + 4 * hi + r > q) s_[ct][r] = -3.0e38f;
      }
      float mt = -3.0e38f;
#pragma unroll
      for (int ct = 0; ct < 4; ct++)
        mt = fmaxf(mt, fmaxf(fmaxf(s_[ct][0], s_[ct][1]), fmaxf(s_[ct][2], s_[ct][3])));
      mt = fmaxf(mt, __shfl_xor(mt, 16));
      mt = fmaxf(mt, __shfl_xor(mt, 32));
      float mn = mreg[s];
      if (!__all(mt <= mn + 8.f)) {
        mn = fmaxf(mn, mt);
        const float al = EXP2(mreg[s] - mn);
        mreg[s] = mn;
        lsum[s] *= al;
#pragma unroll
        for (int ct = 0; ct < 4; ct++)
#pragma unroll
          for (int r = 0; r < 4; r++) oacc[s][ct][r] *= al;
      }
      float rs = 0.f;
#pragma unroll
      for (int ct = 0; ct < 4; ct++)
#pragma unroll
        for (int r = 0; r < 4; r++) {
          float p = EXP2(s_[ct][r] - mn);
          rs += p;
          pb[s][ct][r] = (f16)p;
        }
      rs += __shfl_xor(rs, 16);
      rs += __shfl_xor(rs, 32);
      lsum[s] += rs;
    }

    lds_cp vtrb = (lds_cp)(smem + 16384 + cur * 8192) + lane * 8;
#pragma unroll
    for (int ct = 0; ct < 4; ct++) {
      lds_cp bct = vtrb + ct * 2048;
      f16x4 v0, v1, v2, v3;
      TR16(v0, bct, "0");
      TR16(v1, bct, "512");
      TR16(v2, bct, "1024");
      TR16(v3, bct, "1536");
      asm volatile("s_waitcnt lgkmcnt(0)" ::: "memory");
      __builtin_amdgcn_sched_barrier(0);
      __builtin_amdgcn_s_setprio(1);
      if (act0) {
        oacc[0][ct] = MFMA16(v0, pb[0][0], oacc[0][ct]);
        oacc[0][ct] = MFMA16(v1, pb[0][1], oacc[0][ct]);
        oacc[0][ct] = MFMA16(v2, pb[0][2], oacc[0][ct]);
        oacc[0][ct] = MFMA16(v3, pb[0][3], oacc[0][ct]);
      }
      oacc[1][ct] = MFMA16(v0, pb[1][0], oacc[1][ct]);
      oacc[1][ct] = MFMA16(v1, pb[1][1], oacc[1][ct]);
      oacc[1][ct] = MFMA16(v2, pb[1][2], oacc[1][ct]);
      oacc[1][ct] = MFMA16(v3, pb[1][3], oacc[1][ct]);
      __builtin_amdgcn_s_setprio(0);
    }

    asm volatile("s_waitcnt vmcnt(0)" ::: "memory");
    __builtin_amdgcn_s_barrier();
  }

#pragma unroll
  for (int s = 0; s < 2; s++) {
    __syncthreads();
    const float inv = 1.f / lsum[s];
#pragma unroll
    for (int ct = 0; ct < 4; ct++) {
      f16x4 o4;
#pragma unroll
      for (int r = 0; r < 4; r++) o4[r] = (f16)(oacc[s][ct][r] * inv);
      *(f16x4*)&Ol[w * 16 + lo][ct * 16 + 4 * hi] = o4;
    }
    __syncthreads();
#pragma unroll
    for (int i = 0; i < 2; i++) {
      int idx = tid + 256 * i;
      int qq = idx >> 3, ch = idx & 7;
      *(f16x8*)&y[((size_t)b * T + tile[s] * 64 + qq) * 1024 + (size_t)h * 64 + ch * 8] =
          *(const f16x8*)&Ol[qq][ch * 8];
    }
  }
}

extern "C" void kernel_launch(void* const* d_in, const int* in_sizes, int n_in,
                              void* d_out, int out_size, void* d_ws, size_t ws_size,
                              hipStream_t stream) {
  const float* x = (const float*)d_in[0];
  const float* w_qkv = (const float*)d_in[2];
  const float* w_proj = (const float*)d_in[3];

  constexpr int B = 4, T = 2048, C = 1024, NH = 16;
  constexpr int M = B * T;   // 8192
  constexpr int N1 = 3 * C;  // 3072

  char* ws = (char*)d_ws;
  f16* x16 = (f16*)ws;    ws += (size_t)M * C * 2;
  f16* wqkvT = (f16*)ws;  ws += (size_t)N1 * C * 2;
  f16* wprojT = (f16*)ws; ws += (size_t)C * C * 2;
  f16* qkvb = (f16*)ws;   ws += (size_t)M * N1 * 2;
  f16* y16 = (f16*)ws;

  cast_f32_f16_kernel<<<(M * C / 4 + 255) / 256, 256, 0, stream>>>(x, x16, M * C / 4);
  transpose_cast_kernel<<<dim3(N1 / 32, C / 32), 256, 0, stream>>>(w_qkv, wqkvT, C, N1);
  transpose_cast_kernel<<<dim3(C / 32, C / 32), 256, 0, stream>>>(w_proj, wprojT, C, C);
  gemm_bt_kernel<<<(M / 256) * (N1 / 128), 256, 0, stream>>>(x16, wqkvT, qkvb, M, N1, C);
  attn_kernel<<<dim3(B * NH, 16), 256, 0, stream>>>(qkvb, y16);
  gemm_f16_kernel<true><<<dim3(C / 128, M / 128), 256, 0, stream>>>(y16, wprojT, (float*)d_out, M, C, C);
}

// Round 9
// 171.533 us; speedup vs baseline: 1.5559x; 1.5559x over previous
//
#include <hip/hip_runtime.h>
#include <hip/hip_bf16.h>

typedef _Float16 f16;
typedef __attribute__((ext_vector_type(4))) _Float16 f16x4;
typedef __attribute__((ext_vector_type(8))) _Float16 f16x8;
typedef __attribute__((ext_vector_type(4))) float f32x4;

#define MFMA16(a, b, c) __builtin_amdgcn_mfma_f32_16x16x16f16((a), (b), (c), 0, 0, 0)
#define MFMA32(a, b, c) __builtin_amdgcn_mfma_f32_16x16x32_f16((a), (b), (c), 0, 0, 0)
#define EXP2(x) __builtin_amdgcn_exp2f(x)
#define GLOAD_LDS16(g, l)                                                        \
  __builtin_amdgcn_global_load_lds((const __attribute__((address_space(1))) void*)(g), \
                                   (__attribute__((address_space(3))) void*)(l), 16, 0, 0)
typedef const __attribute__((address_space(3))) char* lds_cp;
#define TR16(dst, addr, imm) \
  asm volatile("ds_read_b64_tr_b16 %0, %1 offset:" imm : "=v"(dst) : "v"(addr))

__device__ __forceinline__ float max3f(float a, float b, float c) {
  return fmaxf(fmaxf(a, b), c);  // folds to v_max3_f32
}

// ---------------- fused prep: cast x + transpose both weights ----------------
// blocks [0,8192): cast x f32->f16 (f16x4 per thread)
// blocks [8192,11264): transpose w_qkv [1024][3072] -> [3072][1024]
// blocks [11264,12288): transpose w_proj [1024][1024] -> [1024][1024]
__global__ __launch_bounds__(256) void prep_kernel(
    const float* __restrict__ x, f16* __restrict__ x16,
    const float* __restrict__ wq, f16* __restrict__ wqT,
    const float* __restrict__ wp, f16* __restrict__ wpT) {
  const int blk = blockIdx.x;
  const int tid = threadIdx.x;
  if (blk < 8192) {
    int i = blk * 256 + tid;
    const float4 v = reinterpret_cast<const float4*>(x)[i];
    f16x4 h;
    h[0] = (f16)v.x; h[1] = (f16)v.y; h[2] = (f16)v.z; h[3] = (f16)v.w;
    reinterpret_cast<f16x4*>(x16)[i] = h;
    return;
  }
  const float* src;
  f16* dst;
  int R, Cc, bx, by;
  if (blk < 11264) {
    int j = blk - 8192;
    bx = j % 96; by = j / 96;
    src = wq; dst = wqT; R = 1024; Cc = 3072;
  } else {
    int j = blk - 11264;
    bx = j & 31; by = j >> 5;
    src = wp; dst = wpT; R = 1024; Cc = 1024;
  }
  __shared__ float t[32][33];
  int tx0 = bx * 32, ty0 = by * 32;
  int c = tid & 31;
  int r0 = tid >> 5;
#pragma unroll
  for (int i = 0; i < 4; i++) {
    int r = r0 + 8 * i;
    t[r][c] = src[(size_t)(ty0 + r) * Cc + tx0 + c];
  }
  __syncthreads();
#pragma unroll
  for (int i = 0; i < 4; i++) {
    int a = r0 + 8 * i;
    dst[(size_t)(tx0 + a) * R + ty0 + c] = (f16)t[c][a];
  }
}

// ============ 256x256 8-phase GEMM (m201 template) — QKV ============
__global__ __launch_bounds__(512, 2) void gemm256_8ph_kernel(
    const f16* __restrict__ A, const f16* __restrict__ Bt, f16* __restrict__ C,
    int M, int N, int K) {
  __shared__ __align__(16) char smem[131072];
  const int tid = threadIdx.x;
  const int lane = tid & 63, wid = tid >> 6;
  const int wm = wid >> 2, wn = wid & 3;  // 2 x 4 waves, wave tile 128 x 64
  const int lo = lane & 15, hi = lane >> 4;

  const int ntn = N >> 8;
  const int nwg = (M >> 8) * ntn;
  const int wg = (blockIdx.x & 7) * (nwg >> 3) + (blockIdx.x >> 3);
  const int tm0 = (wg / ntn) << 8, tn0 = (wg % ntn) << 8;

  const int sr = tid >> 3;
  const int sc8 = (tid & 7) ^ (sr & 7);

  const int sw = lo & 7;
  const int aoff0 = wm * 16384 + lo * 128 + ((hi ^ sw) << 4);
  const int aoff1 = wm * 16384 + lo * 128 + (((4 + hi) ^ sw) << 4);
  const int brow = ((wn & 1) * 64 + lo) * 128;
  const int boff0 = 32768 + (wn >> 1) * 16384 + brow + ((hi ^ sw) << 4);
  const int boff1 = 32768 + (wn >> 1) * 16384 + brow + (((4 + hi) ^ sw) << 4);

  f32x4 acc[8][4] = {};

  const int nslots = K >> 4;
  auto stage_slot = [&](int s) {
    if (s >= nslots) return;
    const int kt = s >> 2, ct = s & 3;
    char* dst = smem + (kt & 1) * 65536 + ct * 16384 + tid * 16;
    const f16* src = (ct < 2) ? (A + (size_t)(tm0 + (ct & 1) * 128) * K)
                              : (Bt + (size_t)(tn0 + (ct & 1) * 128) * K);
    const f16* p = src + (size_t)sr * K + kt * 64 + sc8 * 8;
    GLOAD_LDS16(p, dst);
    GLOAD_LDS16(p + ((size_t)K << 6), dst + 8192);
  };

  auto ktile4 = [&](const char* db, int sb) {
    f16x8 a[4][2], bA[2][2], bB[2][2];
    asm volatile("s_waitcnt vmcnt(2)" ::: "memory");
    __builtin_amdgcn_s_barrier();
#pragma unroll
    for (int mi = 0; mi < 4; mi++) {
      a[mi][0] = *(const f16x8*)(db + aoff0 + mi * 2048);
      a[mi][1] = *(const f16x8*)(db + aoff1 + mi * 2048);
    }
#pragma unroll
    for (int nn = 0; nn < 2; nn++) {
      bA[nn][0] = *(const f16x8*)(db + boff0 + nn * 2048);
      bA[nn][1] = *(const f16x8*)(db + boff1 + nn * 2048);
    }
    stage_slot(sb);
    __builtin_amdgcn_s_barrier();
    asm volatile("s_waitcnt lgkmcnt(0)" ::: "memory");
    __builtin_amdgcn_sched_barrier(0);
    __builtin_amdgcn_s_setprio(1);
#pragma unroll
    for (int mi = 0; mi < 4; mi++)
#pragma unroll
      for (int nn = 0; nn < 2; nn++) {
        acc[mi][nn] = MFMA32(a[mi][0], bA[nn][0], acc[mi][nn]);
        acc[mi][nn] = MFMA32(a[mi][1], bA[nn][1], acc[mi][nn]);
      }
    __builtin_amdgcn_s_setprio(0);
    __builtin_amdgcn_s_barrier();
#pragma unroll
    for (int nn = 0; nn < 2; nn++) {
      bB[nn][0] = *(const f16x8*)(db + boff0 + (2 + nn) * 2048);
      bB[nn][1] = *(const f16x8*)(db + boff1 + (2 + nn) * 2048);
    }
    stage_slot(sb + 1);
    __builtin_amdgcn_s_barrier();
    asm volatile("s_waitcnt lgkmcnt(0)" ::: "memory");
    __builtin_amdgcn_sched_barrier(0);
    __builtin_amdgcn_s_setprio(1);
#pragma unroll
    for (int mi = 0; mi < 4; mi++)
#pragma unroll
      for (int nn = 0; nn < 2; nn++) {
        acc[mi][2 + nn] = MFMA32(a[mi][0], bB[nn][0], acc[mi][2 + nn]);
        acc[mi][2 + nn] = MFMA32(a[mi][1], bB[nn][1], acc[mi][2 + nn]);
      }
    __builtin_amdgcn_s_setprio(0);
    __builtin_amdgcn_s_barrier();
#pragma unroll
    for (int mi = 0; mi < 4; mi++) {
      a[mi][0] = *(const f16x8*)(db + aoff0 + 8192 + mi * 2048);
      a[mi][1] = *(const f16x8*)(db + aoff1 + 8192 + mi * 2048);
    }
    stage_slot(sb + 2);
    __builtin_amdgcn_s_barrier();
    asm volatile("s_waitcnt lgkmcnt(0)" ::: "memory");
    __builtin_amdgcn_sched_barrier(0);
    __builtin_amdgcn_s_setprio(1);
#pragma unroll
    for (int mi = 0; mi < 4; mi++)
#pragma unroll
      for (int nn = 0; nn < 2; nn++) {
        acc[4 + mi][nn] = MFMA32(a[mi][0], bA[nn][0], acc[4 + mi][nn]);
        acc[4 + mi][nn] = MFMA32(a[mi][1], bA[nn][1], acc[4 + mi][nn]);
      }
    __builtin_amdgcn_s_setprio(0);
    __builtin_amdgcn_s_barrier();
    stage_slot(sb + 3);
    __builtin_amdgcn_s_barrier();
    __builtin_amdgcn_s_setprio(1);
#pragma unroll
    for (int mi = 0; mi < 4; mi++)
#pragma unroll
      for (int nn = 0; nn < 2; nn++) {
        acc[4 + mi][2 + nn] = MFMA32(a[mi][0], bB[nn][0], acc[4 + mi][2 + nn]);
        acc[4 + mi][2 + nn] = MFMA32(a[mi][1], bB[nn][1], acc[4 + mi][2 + nn]);
      }
    __builtin_amdgcn_s_setprio(0);
  };

  for (int s = 0; s < 5; s++) stage_slot(s);
  asm volatile("s_waitcnt vmcnt(2)" ::: "memory");
  __builtin_amdgcn_s_barrier();

  const int NI = K >> 7;
  for (int t = 0; t < NI; t++) {
    ktile4(smem, 8 * t + 5);
    ktile4(smem + 65536, 8 * t + 9);
  }

#pragma unroll
  for (int mi = 0; mi < 8; mi++)
#pragma unroll
    for (int ni = 0; ni < 4; ni++)
#pragma unroll
      for (int r = 0; r < 4; r++) {
        int row = tm0 + wm * 128 + mi * 16 + 4 * hi + r;
        int col = tn0 + wn * 64 + ni * 16 + lo;
        C[(size_t)row * N + col] = (f16)acc[mi][ni][r];
      }
}

// ---------------- GEMM (128^2, triple-buffered counted vmcnt) — proj ----------------
template <bool OUT_F32>
__global__ __launch_bounds__(256) void gemm_f16_kernel(
    const f16* __restrict__ A, const f16* __restrict__ Bt, void* __restrict__ Cout,
    int M, int N, int K) {
  constexpr int BK = 32;
  __shared__ f16 Al[3][128 * BK];
  __shared__ f16 Bl[3][128 * BK];

  const int tid = threadIdx.x;
  const int lane = tid & 63, wid = tid >> 6;
  const int wm = wid >> 1, wn = wid & 1;
  const int lo = lane & 15, hi = lane >> 4;
  const int tn0 = blockIdx.x * 128, tm0 = blockIdx.y * 128;

  f32x4 acc[4][4] = {};

  const int r1 = tid >> 2, o1 = (tid & 3) * 8;

  auto stage = [&](int kt, int c) {
    GLOAD_LDS16(&A[(size_t)(tm0 + r1) * K + kt + o1], &Al[c][tid * 8]);
    GLOAD_LDS16(&A[(size_t)(tm0 + r1 + 64) * K + kt + o1], &Al[c][(tid + 256) * 8]);
    GLOAD_LDS16(&Bt[(size_t)(tn0 + r1) * K + kt + o1], &Bl[c][tid * 8]);
    GLOAD_LDS16(&Bt[(size_t)(tn0 + r1 + 64) * K + kt + o1], &Bl[c][(tid + 256) * 8]);
  };

  auto compute = [&](int cur) {
    f16x8 af[4], bf[4];
#pragma unroll
    for (int mi = 0; mi < 4; mi++)
      af[mi] = *(const f16x8*)&Al[cur][(wm * 64 + mi * 16 + lo) * BK + 8 * hi];
#pragma unroll
    for (int ni = 0; ni < 4; ni++)
      bf[ni] = *(const f16x8*)&Bl[cur][(wn * 64 + ni * 16 + lo) * BK + 8 * hi];
    __builtin_amdgcn_s_setprio(1);
#pragma unroll
    for (int mi = 0; mi < 4; mi++)
#pragma unroll
      for (int ni = 0; ni < 4; ni++)
        acc[mi][ni] = MFMA32(af[mi], bf[ni], acc[mi][ni]);
    __builtin_amdgcn_s_setprio(0);
  };

  const int NT = K / BK;
  stage(0, 0);
  stage(BK, 1);

  int cur = 0;
  for (int t = 0; t < NT - 1; t++) {
    asm volatile("s_waitcnt vmcnt(4)" ::: "memory");
    __builtin_amdgcn_s_barrier();
    if (t + 2 < NT) stage((t + 2) * BK, (t + 2) % 3);
    compute(cur);
    cur = (cur == 2) ? 0 : cur + 1;
  }
  asm volatile("s_waitcnt vmcnt(0)" ::: "memory");
  __builtin_amdgcn_s_barrier();
  compute(cur);

#pragma unroll
  for (int mi = 0; mi < 4; mi++)
#pragma unroll
    for (int ni = 0; ni < 4; ni++)
#pragma unroll
      for (int r = 0; r < 4; r++) {
        int row = tm0 + wm * 64 + mi * 16 + 4 * hi + r;
        int col = tn0 + wn * 64 + ni * 16 + lo;
        float v = acc[mi][ni][r];
        if (OUT_F32)
          ((float*)Cout)[(size_t)row * N + col] = v;
        else
          ((f16*)Cout)[(size_t)row * N + col] = (f16)v;
      }
}

// ---------------- causal flash attention ----------------
// lsum computed on the MFMA pipe (1^T x P^T); max via v_max3 tree.
__global__ __launch_bounds__(256, 4) void attn_kernel(
    const f16* __restrict__ qkv, f16* __restrict__ y) {
  constexpr int T = 2048, NHD = 3072, LDO = 72;
  const int bh = blockIdx.x;
  const int b = bh >> 4, h = bh & 15;
  const int pr = blockIdx.y;
  const int tid = threadIdx.x;
  const int lane = tid & 63, w = tid >> 6;
  const int lo = lane & 15, hi = lane >> 4;

  const size_t base = (size_t)b * T * NHD + (size_t)h * 64;
  const f16* Qp = qkv + base;
  const f16* Kp = qkv + base + 1024;
  const f16* Vp = qkv + base + 2048;

  __shared__ __align__(16) char smem[32768];
  f16 (*Ol)[LDO] = (f16(*)[LDO])smem;

  const int tile[2] = {pr, 31 - pr};
  const int qb[2] = {tile[0] * 64 + w * 16, tile[1] * 64 + w * 16};

  const float scf = 0.125f * 1.44269504089f;
  f16x8 qf[2][2];
#pragma unroll
  for (int s = 0; s < 2; s++) {
    const f16* qrow = Qp + (size_t)(qb[s] + lo) * NHD;
#pragma unroll
    for (int ks = 0; ks < 2; ks++) {
      f16x8 v = *(const f16x8*)&qrow[ks * 32 + 8 * hi];
#pragma unroll
      for (int j = 0; j < 8; j++) v[j] = (f16)((float)v[j] * scf);
      qf[s][ks] = v;
    }
  }

  f32x4 oacc[2][4] = {};
  f32x4 lacc[2] = {};               // lsum accumulator via MFMA (1^T P^T)
  float mreg[2] = {-1e30f, -1e30f};
  const f16x4 ones4 = {(f16)1.f, (f16)1.f, (f16)1.f, (f16)1.f};

  const int kr = tid >> 3;
  const int kslot = (tid & 7) ^ (kr & 7);
  const int tp = tid & 127;
  const int vkey = 4 * (tp >> 3) + ((tp >> 1) & 3);
  const int vcol = (tid >> 7) * 16 + (tid & 1) * 8;

  const int kfo0 = lo * 64 + ((hi ^ (lo & 7)) * 8);
  const int kfo1 = lo * 64 + (((4 + hi) ^ (lo & 7)) * 8);

  auto stage = [&](int kv, int c) {
    char* kb = smem + c * 8192;
    char* vb = smem + 16384 + c * 8192;
    GLOAD_LDS16(&Kp[(size_t)(kv + kr) * NHD + kslot * 8], kb + tid * 16);
    GLOAD_LDS16(&Kp[(size_t)(kv + kr + 32) * NHD + kslot * 8], kb + 4096 + tid * 16);
    GLOAD_LDS16(&Vp[(size_t)(kv + vkey) * NHD + vcol], vb + tid * 16);
    GLOAD_LDS16(&Vp[(size_t)(kv + vkey) * NHD + vcol + 32], vb + 4096 + tid * 16);
  };

  const int nt = 32 - pr;
  stage(0, 0);
  asm volatile("s_waitcnt vmcnt(0)" ::: "memory");
  __builtin_amdgcn_s_barrier();

  for (int t = 0; t < nt; t++) {
    const int cur = t & 1;
    const int kv0 = t * 64;
    if (t + 1 < nt) stage(kv0 + 64, cur ^ 1);

    const f16* Kl = (const f16*)(smem + cur * 8192);
    const bool act0 = kv0 <= qb[0] + 15;

    f16x8 kf[2][4];
#pragma unroll
    for (int ct = 0; ct < 4; ct++) {
      kf[0][ct] = *(const f16x8*)&Kl[ct * 1024 + kfo0];
      kf[1][ct] = *(const f16x8*)&Kl[ct * 1024 + kfo1];
    }

    f16x4 pb[2][4];
#pragma unroll
    for (int s = 0; s < 2; s++) {
      if (s == 0 && !act0) continue;
      f32x4 s_[4] = {};
      __builtin_amdgcn_s_setprio(1);
#pragma unroll
      for (int ks = 0; ks < 2; ks++)
#pragma unroll
        for (int ct = 0; ct < 4; ct++)
          s_[ct] = MFMA32(kf[ks][ct], qf[s][ks], s_[ct]);
      __builtin_amdgcn_s_setprio(0);

      if (kv0 + 63 > qb[s]) {
        const int q = qb[s] + lo;
#pragma unroll
        for (int ct = 0; ct < 4; ct++)
#pragma unroll
          for (int r = 0; r < 4; r++)
            if (kv0 + ct * 16 + 4 * hi + r > q) s_[ct][r] = -3.0e38f;
      }
      // row max via v_max3 tree (16 -> 7 ops)
      float t0 = max3f(s_[0][0], s_[0][1], s_[0][2]);
      float t1 = max3f(s_[0][3], s_[1][0], s_[1][1]);
      float t2 = max3f(s_[1][2], s_[1][3], s_[2][0]);
      float t3 = max3f(s_[2][1], s_[2][2], s_[2][3]);
      float t4 = max3f(s_[3][0], s_[3][1], s_[3][2]);
      float mt = fmaxf(max3f(t0, t1, t2), max3f(t3, t4, s_[3][3]));
      mt = fmaxf(mt, __shfl_xor(mt, 16));
      mt = fmaxf(mt, __shfl_xor(mt, 32));
      float mn = mreg[s];
      if (!__all(mt <= mn + 8.f)) {  // defer-max (T13)
        mn = fmaxf(mn, mt);
        const float al = EXP2(mreg[s] - mn);
        mreg[s] = mn;
#pragma unroll
        for (int r = 0; r < 4; r++) lacc[s][r] *= al;
#pragma unroll
        for (int ct = 0; ct < 4; ct++)
#pragma unroll
          for (int r = 0; r < 4; r++) oacc[s][ct][r] *= al;
      }
#pragma unroll
      for (int ct = 0; ct < 4; ct++)
#pragma unroll
        for (int r = 0; r < 4; r++)
          pb[s][ct][r] = (f16)EXP2(s_[ct][r] - mn);
      // lsum on the MFMA pipe: lacc += 1^T x P^T
      __builtin_amdgcn_s_setprio(1);
#pragma unroll
      for (int kk = 0; kk < 4; kk++)
        lacc[s] = MFMA16(ones4, pb[s][kk], lacc[s]);
      __builtin_amdgcn_s_setprio(0);
    }

    lds_cp vtrb = (lds_cp)(smem + 16384 + cur * 8192) + lane * 8;
#pragma unroll
    for (int ct = 0; ct < 4; ct++) {
      lds_cp bct = vtrb + ct * 2048;
      f16x4 v0, v1, v2, v3;
      TR16(v0, bct, "0");
      TR16(v1, bct, "512");
      TR16(v2, bct, "1024");
      TR16(v3, bct, "1536");
      asm volatile("s_waitcnt lgkmcnt(0)" ::: "memory");
      __builtin_amdgcn_sched_barrier(0);
      __builtin_amdgcn_s_setprio(1);
      if (act0) {
        oacc[0][ct] = MFMA16(v0, pb[0][0], oacc[0][ct]);
        oacc[0][ct] = MFMA16(v1, pb[0][1], oacc[0][ct]);
        oacc[0][ct] = MFMA16(v2, pb[0][2], oacc[0][ct]);
        oacc[0][ct] = MFMA16(v3, pb[0][3], oacc[0][ct]);
      }
      oacc[1][ct] = MFMA16(v0, pb[1][0], oacc[1][ct]);
      oacc[1][ct] = MFMA16(v1, pb[1][1], oacc[1][ct]);
      oacc[1][ct] = MFMA16(v2, pb[1][2], oacc[1][ct]);
      oacc[1][ct] = MFMA16(v3, pb[1][3], oacc[1][ct]);
      __builtin_amdgcn_s_setprio(0);
    }

    asm volatile("s_waitcnt vmcnt(0)" ::: "memory");
    __builtin_amdgcn_s_barrier();
  }

#pragma unroll
  for (int s = 0; s < 2; s++) {
    __syncthreads();
    const float inv = 1.f / lacc[s][0];  // every lane holds its q's row-sum
#pragma unroll
    for (int ct = 0; ct < 4; ct++) {
      f16x4 o4;
#pragma unroll
      for (int r = 0; r < 4; r++) o4[r] = (f16)(oacc[s][ct][r] * inv);
      *(f16x4*)&Ol[w * 16 + lo][ct * 16 + 4 * hi] = o4;
    }
    __syncthreads();
#pragma unroll
    for (int i = 0; i < 2; i++) {
      int idx = tid + 256 * i;
      int qq = idx >> 3, ch = idx & 7;
      *(f16x8*)&y[((size_t)b * T + tile[s] * 64 + qq) * 1024 + (size_t)h * 64 + ch * 8] =
          *(const f16x8*)&Ol[qq][ch * 8];
    }
  }
}

extern "C" void kernel_launch(void* const* d_in, const int* in_sizes, int n_in,
                              void* d_out, int out_size, void* d_ws, size_t ws_size,
                              hipStream_t stream) {
  const float* x = (const float*)d_in[0];
  const float* w_qkv = (const float*)d_in[2];
  const float* w_proj = (const float*)d_in[3];

  constexpr int B = 4, T = 2048, C = 1024, NH = 16;
  constexpr int M = B * T;   // 8192
  constexpr int N1 = 3 * C;  // 3072

  char* ws = (char*)d_ws;
  f16* x16 = (f16*)ws;    ws += (size_t)M * C * 2;
  f16* wqkvT = (f16*)ws;  ws += (size_t)N1 * C * 2;
  f16* wprojT = (f16*)ws; ws += (size_t)C * C * 2;
  f16* qkvb = (f16*)ws;   ws += (size_t)M * N1 * 2;
  f16* y16 = (f16*)ws;

  prep_kernel<<<12288, 256, 0, stream>>>(x, x16, w_qkv, wqkvT, w_proj, wprojT);
  gemm256_8ph_kernel<<<(M / 256) * (N1 / 256), 512, 0, stream>>>(x16, wqkvT, qkvb, M, N1, C);
  attn_kernel<<<dim3(B * NH, 16), 256, 0, stream>>>(qkvb, y16);
  gemm_f16_kernel<true><<<dim3(C / 128, M / 128), 256, 0, stream>>>(y16, wprojT, (float*)d_out, M, C, C);
}